// Round 1
// baseline (189.604 us; speedup 1.0000x reference)
//
#include <hip/hip_runtime.h>

#define N_PTS 128
#define EPS_F 1e-10f
#define FAR_F 1e10f

// One 64-lane wave per ray; lane l owns points 2l and 2l+1.
// cumprod via shfl_up multiply-scan; rgb/depth via shfl_xor butterfly.
__global__ __launch_bounds__(256) void volrend_kernel(
        const float* __restrict__ density,
        const float* __restrict__ feature,
        const float* __restrict__ depth,
        float* __restrict__ out, int n_rays) {
    const int lane = threadIdx.x & 63;
    const int ray  = blockIdx.x * 4 + (threadIdx.x >> 6);
    if (ray >= n_rays) return;

    // Coalesced vector loads: 8 B/lane for density/depth, 24 B/lane feature.
    const float2 dns = ((const float2*)(density + (size_t)ray * N_PTS))[lane];
    const float2 z   = ((const float2*)(depth   + (size_t)ray * N_PTS))[lane];
    const float2* fp = (const float2*)(feature + (size_t)ray * (N_PTS * 3));
    const float2 fa = fp[lane * 3 + 0];   // feat[2l].x, feat[2l].y
    const float2 fb = fp[lane * 3 + 1];   // feat[2l].z, feat[2l+1].x
    const float2 fc = fp[lane * 3 + 2];   // feat[2l+1].y, feat[2l+1].z

    // deltas: next sample depth minus this one; last delta = 1e10
    float nz     = __shfl_down(z.x, 1, 64);            // depth[2l+2]
    float delta0 = z.y - z.x;
    float delta1 = (lane == 63) ? FAR_F : (nz - z.y);

    float e0 = __expf(-delta0 * dns.x);
    float e1 = __expf(-delta1 * dns.y);
    float alpha0 = 1.0f - e0;
    float alpha1 = 1.0f - e1;
    float f0 = e0 + EPS_F;                // 1 - alpha + eps
    float f1 = e1 + EPS_F;

    // Inclusive product-scan of per-lane factor across the wave.
    float p = f0 * f1;
    #pragma unroll
    for (int off = 1; off < 64; off <<= 1) {
        float t = __shfl_up(p, off, 64);
        p *= (lane >= off) ? t : 1.0f;
    }
    // Exclusive: transmittance entering point 2l.
    float Texcl = __shfl_up(p, 1, 64);
    float T0 = (lane == 0) ? 1.0f : Texcl;

    float w0 = T0 * alpha0;
    float T1 = T0 * f0;
    float w1 = T1 * alpha1;

    // Per-lane partial sums.
    float rx = w0 * fa.x + w1 * fb.y;
    float ry = w0 * fa.y + w1 * fc.x;
    float rz = w0 * fb.x + w1 * fc.y;
    float dd = w0 * z.x  + w1 * z.y;

    // Wave reduction (butterfly).
    #pragma unroll
    for (int off = 32; off > 0; off >>= 1) {
        rx += __shfl_xor(rx, off, 64);
        ry += __shfl_xor(ry, off, 64);
        rz += __shfl_xor(rz, off, 64);
        dd += __shfl_xor(dd, off, 64);
    }

    if (lane == 0) {
        float* o  = out + (size_t)ray * 3;
        o[0] = rx; o[1] = ry; o[2] = rz;
        float* od = out + (size_t)n_rays * 3 + (size_t)ray * 3;
        od[0] = dd; od[1] = dd; od[2] = dd;
    }
}

extern "C" void kernel_launch(void* const* d_in, const int* in_sizes, int n_in,
                              void* d_out, int out_size, void* d_ws, size_t ws_size,
                              hipStream_t stream) {
    const float* density = (const float*)d_in[0];
    const float* feature = (const float*)d_in[1];
    const float* depth   = (const float*)d_in[2];
    float* out = (float*)d_out;
    const int n_rays = in_sizes[0] / N_PTS;   // 65536
    const int blocks = (n_rays + 3) / 4;      // 4 rays (waves) per 256-thread block
    volrend_kernel<<<blocks, 256, 0, stream>>>(density, feature, depth, out, n_rays);
}

// Round 2
// 187.887 us; speedup vs baseline: 1.0091x; 1.0091x over previous
//
#include <hip/hip_runtime.h>

#define N_PTS 128
#define EPS_F 1e-10f
#define FAR_F 1e10f

// DPP ctrl encodings (gfx9/CDNA):
//   ROW_SHR1=0x111 SHR2=0x112 SHR4=0x114 SHR8=0x118
//   ROW_BCAST15=0x142 ROW_BCAST31=0x143
//   WAVE_SHL1=0x130 (lane i <- i+1)   WAVE_SHR1=0x138 (lane i <- i-1)
template<int CTRL, int ROW_MASK>
__device__ __forceinline__ float dpp_mov(float src, float old) {
    union { float f; int i; } s, o, r;
    s.f = src; o.f = old;
    r.i = __builtin_amdgcn_update_dpp(o.i, s.i, CTRL, ROW_MASK, 0xF, false);
    return r.f;
}

// Full-wave (64-lane) sum; total lands in lane 63. All on the VALU pipe.
__device__ __forceinline__ float wave64_reduce_add(float x) {
    x += dpp_mov<0x111, 0xF>(x, 0.0f);
    x += dpp_mov<0x112, 0xF>(x, 0.0f);
    x += dpp_mov<0x114, 0xF>(x, 0.0f);
    x += dpp_mov<0x118, 0xF>(x, 0.0f);
    x += dpp_mov<0x142, 0xA>(x, 0.0f);  // row1 += row0.l15, row3 += row2.l15
    x += dpp_mov<0x143, 0xC>(x, 0.0f);  // rows 2,3 += lane31 (rows0+1 sum)
    return x;
}

// One 64-lane wave per ray; lane l owns points 2l and 2l+1.
// Cumprod scan + reductions via DPP (VALU pipe) — zero DS/LDS instructions.
__global__ __launch_bounds__(256) void volrend_kernel(
        const float* __restrict__ density,
        const float* __restrict__ feature,
        const float* __restrict__ depth,
        float* __restrict__ out, int n_rays) {
    const int lane = threadIdx.x & 63;
    const int ray  = blockIdx.x * 4 + (threadIdx.x >> 6);
    if (ray >= n_rays) return;

    // Coalesced vector loads: 8 B/lane density/depth, 24 B/lane feature.
    const float2 dns = ((const float2*)(density + (size_t)ray * N_PTS))[lane];
    const float2 z   = ((const float2*)(depth   + (size_t)ray * N_PTS))[lane];
    const float2* fp = (const float2*)(feature + (size_t)ray * (N_PTS * 3));
    const float2 fa = fp[lane * 3 + 0];   // feat[2l].x, feat[2l].y
    const float2 fb = fp[lane * 3 + 1];   // feat[2l].z, feat[2l+1].x
    const float2 fc = fp[lane * 3 + 2];   // feat[2l+1].y, feat[2l+1].z

    // next sample depth: lane i <- z.x of lane i+1 (wave_shl1); lane 63 -> FAR
    float nz     = dpp_mov<0x130, 0xF>(z.x, 0.0f);
    float delta0 = z.y - z.x;
    float delta1 = (lane == 63) ? FAR_F : (nz - z.y);

    float e0 = __expf(-delta0 * dns.x);
    float e1 = __expf(-delta1 * dns.y);
    float alpha0 = 1.0f - e0;
    float alpha1 = 1.0f - e1;
    float f0 = e0 + EPS_F;                // 1 - alpha + eps
    float f1 = e1 + EPS_F;

    // Inclusive product-scan of per-lane factor (f0*f1) across 64 lanes.
    float p = f0 * f1;
    p *= dpp_mov<0x111, 0xF>(p, 1.0f);    // row_shr:1
    p *= dpp_mov<0x112, 0xF>(p, 1.0f);    // row_shr:2
    p *= dpp_mov<0x114, 0xF>(p, 1.0f);    // row_shr:4
    p *= dpp_mov<0x118, 0xF>(p, 1.0f);    // row_shr:8
    p *= dpp_mov<0x142, 0xA>(p, 1.0f);    // row_bcast15 -> rows 1,3
    p *= dpp_mov<0x143, 0xC>(p, 1.0f);    // row_bcast31 -> rows 2,3
    // Exclusive shift: T entering point 2l; lane 0 gets identity 1.0.
    float T0 = dpp_mov<0x138, 0xF>(p, 1.0f);   // wave_shr:1

    float w0 = T0 * alpha0;
    float T1 = T0 * f0;
    float w1 = T1 * alpha1;

    // Per-lane partials, then wave reduction on the VALU pipe.
    float rx = wave64_reduce_add(w0 * fa.x + w1 * fb.y);
    float ry = wave64_reduce_add(w0 * fa.y + w1 * fc.x);
    float rz = wave64_reduce_add(w0 * fb.x + w1 * fc.y);
    float dd = wave64_reduce_add(w0 * z.x  + w1 * z.y);

    if (lane == 63) {   // totals land in lane 63
        float* o  = out + (size_t)ray * 3;
        o[0] = rx; o[1] = ry; o[2] = rz;
        float* od = out + (size_t)n_rays * 3 + (size_t)ray * 3;
        od[0] = dd; od[1] = dd; od[2] = dd;
    }
}

extern "C" void kernel_launch(void* const* d_in, const int* in_sizes, int n_in,
                              void* d_out, int out_size, void* d_ws, size_t ws_size,
                              hipStream_t stream) {
    const float* density = (const float*)d_in[0];
    const float* feature = (const float*)d_in[1];
    const float* depth   = (const float*)d_in[2];
    float* out = (float*)d_out;
    const int n_rays = in_sizes[0] / N_PTS;   // 65536
    const int blocks = (n_rays + 3) / 4;      // 4 rays (waves) per 256-thread block
    volrend_kernel<<<blocks, 256, 0, stream>>>(density, feature, depth, out, n_rays);
}